// Round 7
// baseline (389.331 us; speedup 1.0000x reference)
//
#include <hip/hip_runtime.h>

#define B_ 4
#define S_ 2048
#define E_ 512
#define H_ 8
#define HD_ 64

typedef float f32x4 __attribute__((ext_vector_type(4)));
typedef __bf16 bf16x8 __attribute__((ext_vector_type(8)));

#define MFMA16(a, b, c) __builtin_amdgcn_mfma_f32_16x16x32_bf16((a), (b), (c), 0, 0, 0)

__device__ __forceinline__ unsigned f2bfu(float f) {
  union { float f; unsigned u; } x; x.f = f;
  return (x.u + 0x8000u) >> 16;
}
__device__ __forceinline__ unsigned pk2bf(float lo, float hi) {
  union { float f; unsigned u; } a, b; a.f = lo; b.f = hi;
  return ((b.u + 0x8000u) & 0xFFFF0000u) | ((a.u + 0x8000u) >> 16);
}
__device__ __forceinline__ float bf2f(unsigned short s) {
  union { unsigned u; float f; } x; x.u = ((unsigned)s) << 16;
  return x.f;
}
__device__ __forceinline__ float fast_exp2(float x) {
  float r;
  __asm__("v_exp_f32 %0, %1" : "=v"(r) : "v"(x));
  return r;
}
// async global->LDS, 16B per lane. LDS dest = wave-uniform base + lane*16.
__device__ __forceinline__ void gload_lds16(const unsigned short* g, unsigned short* l) {
  __builtin_amdgcn_global_load_lds(
      (const __attribute__((address_space(1))) unsigned int*)g,
      (__attribute__((address_space(3))) unsigned int*)l, 16, 0, 0);
}

// ---------------------------------------------------------------------------
// Fused input conversion. blocks 0..2047: x -> xb (bf16).
// blocks 2048..2431: W (128/matrix); 2432..2495: Er (d-permuted); 2496: zero row.
// ---------------------------------------------------------------------------
__global__ __launch_bounds__(256) void conv_all(
    const float* __restrict__ x, const float* __restrict__ Wq,
    const float* __restrict__ Wk, const float* __restrict__ Wv,
    const float* __restrict__ Er, unsigned short* __restrict__ xb,
    unsigned short* __restrict__ wb, unsigned short* __restrict__ erb)
{
  const int bid = blockIdx.x, tid = threadIdx.x;
  if (bid < 2048) {
    size_t i = ((size_t)bid * 256 + tid) * 8;
    float4 f0 = *(const float4*)&x[i];
    float4 f1 = *(const float4*)&x[i + 4];
    uint4 o;
    o.x = pk2bf(f0.x, f0.y); o.y = pk2bf(f0.z, f0.w);
    o.z = pk2bf(f1.x, f1.y); o.w = pk2bf(f1.z, f1.w);
    *(uint4*)&xb[i] = o;
  } else if (bid < 2432) {
    int wz = bid - 2048;
    int z = wz >> 7, mi = wz & 127;
    const float* src = (z == 0) ? Wq : (z == 1) ? Wk : Wv;
    size_t off = (size_t)mi * 2048 + tid * 8;
    float4 f0 = *(const float4*)&src[off];
    float4 f1 = *(const float4*)&src[off + 4];
    uint4 o;
    o.x = pk2bf(f0.x, f0.y); o.y = pk2bf(f0.z, f0.w);
    o.z = pk2bf(f1.x, f1.y); o.w = pk2bf(f1.z, f1.w);
    *(uint4*)&wb[(size_t)z * 262144 + off] = o;
  } else if (bid < 2496) {
    size_t off = (size_t)(bid - 2432) * 2048 + tid * 8;
    int row = (int)(off >> 6), d0 = (int)(off & 63);
    float4 f0 = *(const float4*)&Er[off];
    float4 f1 = *(const float4*)&Er[off + 4];
    float vals[8] = {f0.x, f0.y, f0.z, f0.w, f1.x, f1.y, f1.z, f1.w};
#pragma unroll
    for (int j = 0; j < 8; ++j) {
      int d = d0 + j;
      int dp = (d & 15) * 4 + (d >> 4);
      erb[(size_t)row * 64 + dp] = (unsigned short)f2bfu(vals[j]);
    }
  } else {
    if (tid < 8) *(uint4*)&erb[2048 * 64 + tid * 8] = make_uint4(0, 0, 0, 0);
  }
}

// ---------------------------------------------------------------------------
// QKV projection, pure-bf16 MFMA with global_load_lds staging.
// out[z] = bf16(xb @ wb[z]^T). M=8192,N=512,K=512. grid (64,4,3), 256 thr.
// z<2 (Q,K): d-axis permuted (d' = (d&15)*4 + d>>4) -> b64 stores; Q
//            pre-scaled by 512^-0.5 * log2(e). z==2 (V): canonical.
// ---------------------------------------------------------------------------
__global__ __launch_bounds__(256) void qkv_gemm_mfma(
    const unsigned short* __restrict__ xb, const unsigned short* __restrict__ wb,
    unsigned short* __restrict__ qkvb)
{
  const int z = blockIdx.z;
  const unsigned short* W = wb + (size_t)z * 262144;
  unsigned short* out = qkvb + (size_t)z * (8192u * 512u);
  const int m0 = blockIdx.x * 128, n0 = blockIdx.y * 128;

  __shared__ __align__(16) unsigned short As[128 * 64];
  __shared__ __align__(16) unsigned short Bs[128 * 64];

  const int tid = threadIdx.x;
  const int w = tid >> 6, l = tid & 63, lm = l & 15, lq = l >> 4;
  const int wm = w & 1, wn = w >> 1;

  union u4bf { uint4 u; bf16x8 v; };
  f32x4 acc[4][4];
#pragma unroll
  for (int a = 0; a < 4; ++a)
#pragma unroll
    for (int b = 0; b < 4; ++b) acc[a][b] = (f32x4){0.f, 0.f, 0.f, 0.f};

  for (int k0 = 0; k0 < 512; k0 += 64) {
    const unsigned short* xa = xb + (size_t)m0 * 512 + k0;
    const unsigned short* wz = W + (size_t)n0 * 512 + k0;
    __syncthreads();
#pragma unroll
    for (int rr = 0; rr < 4; ++rr) {
      int cb = rr * 256 + w * 64;
      int s = cb + l;
      int row = s >> 3, c = (s & 7) ^ (row & 7);
      gload_lds16(&xa[(size_t)row * 512 + c * 8], &As[cb * 8]);
      gload_lds16(&wz[(size_t)row * 512 + c * 8], &Bs[cb * 8]);
    }
    __syncthreads();
#pragma unroll
    for (int ka = 0; ka < 2; ++ka) {
      u4bf af[4];
#pragma unroll
      for (int mt = 0; mt < 4; ++mt) {
        int row = wm * 64 + mt * 16 + lm;
        af[mt].u = *(const uint4*)&As[row * 64 + (((ka * 4 + lq) ^ (row & 7)) * 8)];
      }
#pragma unroll
      for (int nt = 0; nt < 4; ++nt) {
        int row = wn * 64 + nt * 16 + lm;
        u4bf bfv;
        bfv.u = *(const uint4*)&Bs[row * 64 + (((ka * 4 + lq) ^ (row & 7)) * 8)];
#pragma unroll
        for (int mt = 0; mt < 4; ++mt) acc[mt][nt] = MFMA16(af[mt].v, bfv.v, acc[mt][nt]);
      }
    }
  }
  if (z < 2) {
    const float m = (z == 0) ? 0.06376695f : 1.0f;  // 512^-0.5 * log2(e) for Q
#pragma unroll
    for (int mt = 0; mt < 4; ++mt)
#pragma unroll
      for (int reg = 0; reg < 4; ++reg) {
        int row = m0 + wm * 64 + mt * 16 + lq * 4 + reg;
        uint2 v = make_uint2(
            pk2bf(acc[mt][0][reg] * m, acc[mt][1][reg] * m),
            pk2bf(acc[mt][2][reg] * m, acc[mt][3][reg] * m));
        *(uint2*)&out[(size_t)row * 512 + n0 + wn * 64 + lm * 4] = v;
      }
  } else {
#pragma unroll
    for (int mt = 0; mt < 4; ++mt)
#pragma unroll
      for (int nt = 0; nt < 4; ++nt)
#pragma unroll
        for (int reg = 0; reg < 4; ++reg)
          out[(size_t)(m0 + wm * 64 + mt * 16 + lq * 4 + reg) * 512 +
              n0 + wn * 64 + nt * 16 + lm] = (unsigned short)f2bfu(acc[mt][nt][reg]);
  }
}

// ---------------------------------------------------------------------------
// V transpose with t-permutation baked in (see R5). grid (32, 8, 4), 256 thr.
// ---------------------------------------------------------------------------
__global__ __launch_bounds__(256) void v_transpose(
    const unsigned short* __restrict__ v, unsigned short* __restrict__ vt)
{
  const int s0 = blockIdx.x * 64, c0 = blockIdx.y * 64, b = blockIdx.z;
  __shared__ __align__(16) unsigned short T[64 * 72];
  const int tid = threadIdx.x;
  for (int idx = tid; idx < 512; idx += 256) {
    int r = idx >> 3, c8 = (idx & 7) * 8;
    *(uint4*)&T[r * 72 + c8] =
        *(const uint4*)&v[(size_t)(b * 2048 + s0 + r) * 512 + c0 + c8];
  }
  __syncthreads();
  for (int idx = tid; idx < 512; idx += 256) {
    int d = idx >> 3, s8 = (idx & 7) * 8;
    union { unsigned short u[8]; uint4 q; } tmp;
#pragma unroll
    for (int j = 0; j < 8; ++j) {
      int p = s8 + j;
      int tsrc = (p & 3) * 16 + (p >> 2);
      tmp.u[j] = T[tsrc * 72 + d];
    }
    *(uint4*)&vt[((size_t)(b * 512) + c0 + d) * 2048 + s0 + s8] = tmp.q;
  }
}

// ---------------------------------------------------------------------------
// Fused attention. Max-free softmax (Q pre-scaled by scale*log2e, raw
// v_exp_f32), l via ones-B MFMA. 2 barriers/iter:
//   (a) sync; stage VTs (DMA); rslab (Er direct from global, row-split:
//       wave w computes Rext rows w*16..+15 using its OWN aqw fragment,
//       all 64 new cols; row 64 via 1-row tile, col-split by wave)
//   (b) sync; QK (K B-frags direct from global, L1-hot); gather+exp+P-write
//       (Ps rows are wave-private -> asm fence, NO barrier); PV.
// Circular Rx[slot=ai&127][isel], stride 68 (8B-aligned b64 writes).
//   ai<64: Er[1984+ai]; ai==64: zero row erb[2048]; ai>64: Er[ai-65], isel=il+1.
// ---------------------------------------------------------------------------
__global__ __launch_bounds__(256, 4) void attn_mfma(
    const unsigned short* __restrict__ qw, const unsigned short* __restrict__ kw,
    const unsigned short* __restrict__ vt, const unsigned short* __restrict__ erb,
    float* __restrict__ out)
{
  const int qb = blockIdx.x, bh = blockIdx.y;
  const int b = bh >> 3, h = bh & 7;
  const int i0 = qb * 64;

  __shared__ __align__(16) unsigned short VTs[64 * 64];  // [d][t'] swizzled
  __shared__ __align__(16) unsigned short Ps[64 * 72];   // P [i][t'] wave-private rows
  __shared__ __align__(16) unsigned short Rx[128 * 68];  // [slot][isel]

  const int tid = threadIdx.x;
  const int w = tid >> 6, l = tid & 63, lm = l & 15, lq = l >> 4;

  const unsigned short* qbase = qw + ((size_t)(b * 2048)) * 512 + h * 64;
  const unsigned short* kbase = kw + ((size_t)(b * 2048)) * 512 + h * 64;
  const unsigned short* vtb = vt + ((size_t)(b * 512 + h * 64)) * 2048;

  union u4bf { uint4 u; bf16x8 v; };

  u4bf ones;
  ones.u = make_uint4(0x3F803F80u, 0x3F803F80u, 0x3F803F80u, 0x3F803F80u);

  // ---- wave's own Q A-fragment (rows w*16+lm) — used by QK AND rslab ----
  u4bf aqw[2];
  {
    int gi = i0 + w * 16 + lm;
    aqw[0].u = *(const uint4*)&qbase[(size_t)gi * 512 + lq * 8];
    aqw[1].u = *(const uint4*)&qbase[(size_t)gi * 512 + 32 + lq * 8];
  }
  // ---- row-64 A-fragment: only lane row lm==0 live (q_{i0+64}) ----
  u4bf aq4[2];
#pragma unroll
  for (int ka = 0; ka < 2; ++ka) {
    if (lm == 0 && i0 + 64 < 2048)
      aq4[ka].u = *(const uint4*)&qbase[(size_t)(i0 + 64) * 512 + ka * 32 + lq * 8];
    else
      aq4[ka].u = make_uint4(0, 0, 0, 0);
  }

  auto stageVT = [&](const unsigned short* srcBase) {
#pragma unroll
    for (int rr = 0; rr < 2; ++rr) {
      int cb = rr * 256 + w * 64;
      int s = cb + l;
      int row = s >> 3, c = (s & 7) ^ (row & 7);
      gload_lds16(&srcBase[(size_t)row * 2048 + c * 8], &VTs[cb * 8]);
    }
  };
  auto erRow = [&](int ai) -> const unsigned short* {
    int g = (ai < 64) ? (1984 + ai) : (ai == 64 ? 2048 : ai - 65);
    return &erb[(size_t)g * 64];
  };
  auto rslab = [&](int A0) {
    // own-row-tile: 4 col-tiles, B direct from global
    f32x4 rc[4];
#pragma unroll
    for (int ct = 0; ct < 4; ++ct) {
      const unsigned short* ep = erRow(A0 + ct * 16 + lm);
      u4bf b0, b1;
      b0.u = *(const uint4*)&ep[lq * 8];
      b1.u = *(const uint4*)&ep[32 + lq * 8];
      rc[ct] = (f32x4){0.f, 0.f, 0.f, 0.f};
      rc[ct] = MFMA16(aqw[0].v, b0.v, rc[ct]);
      rc[ct] = MFMA16(aqw[1].v, b1.v, rc[ct]);
    }
    // row-64 tile: this wave covers col-tile == w (redundant B reload, L1-hot)
    f32x4 r4 = (f32x4){0.f, 0.f, 0.f, 0.f};
    {
      const unsigned short* ep = erRow(A0 + w * 16 + lm);
      u4bf b0, b1;
      b0.u = *(const uint4*)&ep[lq * 8];
      b1.u = *(const uint4*)&ep[32 + lq * 8];
      r4 = MFMA16(aq4[0].v, b0.v, r4);
      r4 = MFMA16(aq4[1].v, b1.v, r4);
    }
#pragma unroll
    for (int ct = 0; ct < 4; ++ct) {
      int slot = (A0 + ct * 16 + lm) & 127;
      *(uint2*)&Rx[slot * 68 + w * 16 + lq * 4] =
          make_uint2(pk2bf(rc[ct][0], rc[ct][1]), pk2bf(rc[ct][2], rc[ct][3]));
    }
    if (lq == 0) {
      int slot = (A0 + w * 16 + lm) & 127;
      Rx[slot * 68 + 64] = (unsigned short)f2bfu(r4[0]);
    }
  };

  // ---- prefill Rx with ai in [-i0, -i0+127] (disjoint slots, no sync) ----
  rslab(-i0);
  rslab(-i0 + 64);

  f32x4 O[5];  // O[4] = row-sum l accumulator
#pragma unroll
  for (int a = 0; a < 5; ++a) O[a] = (f32x4){0.f, 0.f, 0.f, 0.f};

  for (int tb = 0; tb < 32; ++tb) {
    const int t0 = tb * 64, dbase = t0 - i0;
    __syncthreads();  // (a) prior-iter gathers (Rx) + PV (VTs) done

    stageVT(vtb + t0);
    if (tb > 0) rslab(dbase + 63);
    __syncthreads();  // (b) VTs DMA drained + Rx visible

    // ---- QK^T (K B-fragments direct from global, shared across waves) ----
    f32x4 sc[4];
#pragma unroll
    for (int nt = 0; nt < 4; ++nt) {
      const unsigned short* kp = &kbase[(size_t)(t0 + nt * 16 + lm) * 512];
      u4bf bk0, bk1;
      bk0.u = *(const uint4*)&kp[lq * 8];
      bk1.u = *(const uint4*)&kp[32 + lq * 8];
      sc[nt] = (f32x4){0.f, 0.f, 0.f, 0.f};
      sc[nt] = MFMA16(aqw[0].v, bk0.v, sc[nt]);
      sc[nt] = MFMA16(aqw[1].v, bk1.v, sc[nt]);
    }

    // ---- skew gather + exp2, packed b64 P-write (wave-private rows) ----
#pragma unroll
    for (int reg = 0; reg < 4; ++reg) {
      const int il = w * 16 + lq * 4 + reg;
      const int aib = dbase + 63 + lm - il;
      float pv[4];
#pragma unroll
      for (int nt = 0; nt < 4; ++nt) {
        int ai = aib + nt * 16;
        int isel = il + (ai >= 65 ? 1 : 0);
        float rel = bf2f(Rx[(ai & 127) * 68 + isel]);
        pv[nt] = fast_exp2(sc[nt][reg] + rel);
      }
      *(uint2*)&Ps[il * 72 + lm * 4] =
          make_uint2(pk2bf(pv[0], pv[1]), pk2bf(pv[2], pv[3]));
    }
    __asm__ __volatile__("" ::: "memory");  // same-wave DS RAW: in-order DS pipe

    // ---- PV + l ----
#pragma unroll
    for (int ka = 0; ka < 2; ++ka) {
      u4bf ap;
      ap.u = *(const uint4*)&Ps[(w * 16 + lm) * 72 + ka * 32 + lq * 8];
#pragma unroll
      for (int nt = 0; nt < 4; ++nt) {
        int row = nt * 16 + lm;
        u4bf bv;
        bv.u = *(const uint4*)&VTs[row * 64 + (((ka * 4 + lq) ^ (row & 7)) * 8)];
        O[nt] = MFMA16(ap.v, bv.v, O[nt]);
      }
      O[4] = MFMA16(ap.v, ones.v, O[4]);
    }
  }

  // epilogue: every lane holds l in O[4][reg]
  float* ob = out + ((size_t)(b * 2048) + i0) * 512 + h * 64;
#pragma unroll
  for (int reg = 0; reg < 4; ++reg) {
    float inv = 1.f / O[4][reg];
    int i_l = w * 16 + lq * 4 + reg;
#pragma unroll
    for (int nt = 0; nt < 4; ++nt)
      ob[(size_t)i_l * 512 + nt * 16 + lm] = O[nt][reg] * inv;
  }
}

// ---------------------------------------------------------------------------
// In-place LayerNorm over E=512 per (b,s) row. grid 8192, block 256.
// ---------------------------------------------------------------------------
__global__ __launch_bounds__(256) void ln_kernel(
    float* __restrict__ io, const float* __restrict__ gamma,
    const float* __restrict__ beta)
{
  const int row = blockIdx.x;
  float* xr = io + (size_t)row * 512;
  const int tid = threadIdx.x;
  float2 v = *(const float2*)&xr[tid * 2];
  float s = v.x + v.y;
  float sq = v.x * v.x + v.y * v.y;
#pragma unroll
  for (int off = 1; off < 64; off <<= 1) {
    s += __shfl_xor(s, off, 64);
    sq += __shfl_xor(sq, off, 64);
  }
  __shared__ float red[8];
  const int wid = tid >> 6, lane = tid & 63;
  if (lane == 0) { red[wid] = s; red[wid + 4] = sq; }
  __syncthreads();
  s = red[0] + red[1] + red[2] + red[3];
  sq = red[4] + red[5] + red[6] + red[7];
  const float mean = s * (1.f / 512.f);
  float var = sq * (1.f / 512.f) - mean * mean;
  var = fmaxf(var, 0.f);
  const float rstd = rsqrtf(var + 1e-5f);
  float2 g = *(const float2*)&gamma[tid * 2];
  float2 be = *(const float2*)&beta[tid * 2];
  float2 o;
  o.x = (v.x - mean) * rstd * g.x + be.x;
  o.y = (v.y - mean) * rstd * g.y + be.y;
  *(float2*)&xr[tid * 2] = o;
}

extern "C" void kernel_launch(void* const* d_in, const int* in_sizes, int n_in,
                              void* d_out, int out_size, void* d_ws, size_t ws_size,
                              hipStream_t stream) {
  const float* x     = (const float*)d_in[0];
  const float* Wq    = (const float*)d_in[1];
  const float* Wk    = (const float*)d_in[2];
  const float* Wv    = (const float*)d_in[3];
  const float* Er    = (const float*)d_in[4];
  const float* gamma = (const float*)d_in[5];
  const float* beta  = (const float*)d_in[6];
  float* out = (float*)d_out;

  // ws layout (bf16 shorts): qkv 3*8192*512 | vT 4*512*2048 | erb 2049*64 |
  //                          xb 8192*512 | wb 3*512*512      (~41.8 MB)
  unsigned short* qkvb = (unsigned short*)d_ws;
  unsigned short* vtb  = qkvb + (size_t)3 * 8192 * 512;
  unsigned short* erb  = vtb + (size_t)4 * 512 * 2048;
  unsigned short* xb   = erb + (size_t)2049 * 64;
  unsigned short* wb   = xb + (size_t)8192 * 512;
  unsigned short* vb   = qkvb + (size_t)2 * 8192 * 512;

  conv_all<<<dim3(2497), 256, 0, stream>>>(x, Wq, Wk, Wv, Er, xb, wb, erb);
  qkv_gemm_mfma<<<dim3(64, 4, 3), 256, 0, stream>>>(xb, wb, qkvb);
  v_transpose<<<dim3(32, 8, 4), 256, 0, stream>>>(vb, vtb);
  attn_mfma<<<dim3(32, 32), 256, 0, stream>>>(qkvb, qkvb + (size_t)8192 * 512, vtb, erb, out);
  ln_kernel<<<dim3(8192), 256, 0, stream>>>(out, gamma, beta);
}

// Round 8
// 228.988 us; speedup vs baseline: 1.7002x; 1.7002x over previous
//
#include <hip/hip_runtime.h>

#define B_ 4
#define S_ 2048
#define E_ 512
#define H_ 8
#define HD_ 64

typedef float f32x4 __attribute__((ext_vector_type(4)));
typedef __bf16 bf16x8 __attribute__((ext_vector_type(8)));

#define MFMA16(a, b, c) __builtin_amdgcn_mfma_f32_16x16x32_bf16((a), (b), (c), 0, 0, 0)

__device__ __forceinline__ unsigned f2bfu(float f) {
  union { float f; unsigned u; } x; x.f = f;
  return (x.u + 0x8000u) >> 16;
}
__device__ __forceinline__ unsigned pk2bf(float lo, float hi) {
  union { float f; unsigned u; } a, b; a.f = lo; b.f = hi;
  return ((b.u + 0x8000u) & 0xFFFF0000u) | ((a.u + 0x8000u) >> 16);
}
__device__ __forceinline__ float bf2f(unsigned short s) {
  union { unsigned u; float f; } x; x.u = ((unsigned)s) << 16;
  return x.f;
}
__device__ __forceinline__ float fast_exp2(float x) {
  float r;
  __asm__("v_exp_f32 %0, %1" : "=v"(r) : "v"(x));
  return r;
}
// async global->LDS, 16B per lane. LDS dest = wave-uniform base + lane*16.
__device__ __forceinline__ void gload_lds16(const unsigned short* g, unsigned short* l) {
  __builtin_amdgcn_global_load_lds(
      (const __attribute__((address_space(1))) unsigned int*)g,
      (__attribute__((address_space(3))) unsigned int*)l, 16, 0, 0);
}

// ---------------------------------------------------------------------------
// Fused input conversion. blocks 0..2047: x -> xb (bf16).
// blocks 2048..2431: W (128/matrix); 2432..2495: Er (d-permuted); 2496: zero row.
// ---------------------------------------------------------------------------
__global__ __launch_bounds__(256) void conv_all(
    const float* __restrict__ x, const float* __restrict__ Wq,
    const float* __restrict__ Wk, const float* __restrict__ Wv,
    const float* __restrict__ Er, unsigned short* __restrict__ xb,
    unsigned short* __restrict__ wb, unsigned short* __restrict__ erb)
{
  const int bid = blockIdx.x, tid = threadIdx.x;
  if (bid < 2048) {
    size_t i = ((size_t)bid * 256 + tid) * 8;
    float4 f0 = *(const float4*)&x[i];
    float4 f1 = *(const float4*)&x[i + 4];
    uint4 o;
    o.x = pk2bf(f0.x, f0.y); o.y = pk2bf(f0.z, f0.w);
    o.z = pk2bf(f1.x, f1.y); o.w = pk2bf(f1.z, f1.w);
    *(uint4*)&xb[i] = o;
  } else if (bid < 2432) {
    int wz = bid - 2048;
    int z = wz >> 7, mi = wz & 127;
    const float* src = (z == 0) ? Wq : (z == 1) ? Wk : Wv;
    size_t off = (size_t)mi * 2048 + tid * 8;
    float4 f0 = *(const float4*)&src[off];
    float4 f1 = *(const float4*)&src[off + 4];
    uint4 o;
    o.x = pk2bf(f0.x, f0.y); o.y = pk2bf(f0.z, f0.w);
    o.z = pk2bf(f1.x, f1.y); o.w = pk2bf(f1.z, f1.w);
    *(uint4*)&wb[(size_t)z * 262144 + off] = o;
  } else if (bid < 2496) {
    size_t off = (size_t)(bid - 2432) * 2048 + tid * 8;
    int row = (int)(off >> 6), d0 = (int)(off & 63);
    float4 f0 = *(const float4*)&Er[off];
    float4 f1 = *(const float4*)&Er[off + 4];
    float vals[8] = {f0.x, f0.y, f0.z, f0.w, f1.x, f1.y, f1.z, f1.w};
#pragma unroll
    for (int j = 0; j < 8; ++j) {
      int d = d0 + j;
      int dp = (d & 15) * 4 + (d >> 4);
      erb[(size_t)row * 64 + dp] = (unsigned short)f2bfu(vals[j]);
    }
  } else {
    if (tid < 8) *(uint4*)&erb[2048 * 64 + tid * 8] = make_uint4(0, 0, 0, 0);
  }
}

// ---------------------------------------------------------------------------
// QKV projection, pure-bf16 MFMA with global_load_lds staging.
// out[z] = bf16(xb @ wb[z]^T). M=8192,N=512,K=512. grid (64,4,3), 256 thr.
// ALL z: output d-axis permuted within 64-blocks (d' = (d&15)*4 + d>>4)
// -> packed b64 stores. Q pre-scaled by 512^-0.5 * log2(e).
// V's permutation is undone (free) inside v_transpose's row relabel.
// ---------------------------------------------------------------------------
__global__ __launch_bounds__(256) void qkv_gemm_mfma(
    const unsigned short* __restrict__ xb, const unsigned short* __restrict__ wb,
    unsigned short* __restrict__ qkvb)
{
  const int z = blockIdx.z;
  const unsigned short* W = wb + (size_t)z * 262144;
  unsigned short* out = qkvb + (size_t)z * (8192u * 512u);
  const int m0 = blockIdx.x * 128, n0 = blockIdx.y * 128;

  __shared__ __align__(16) unsigned short As[128 * 64];
  __shared__ __align__(16) unsigned short Bs[128 * 64];

  const int tid = threadIdx.x;
  const int w = tid >> 6, l = tid & 63, lm = l & 15, lq = l >> 4;
  const int wm = w & 1, wn = w >> 1;

  union u4bf { uint4 u; bf16x8 v; };
  f32x4 acc[4][4];
#pragma unroll
  for (int a = 0; a < 4; ++a)
#pragma unroll
    for (int b = 0; b < 4; ++b) acc[a][b] = (f32x4){0.f, 0.f, 0.f, 0.f};

  for (int k0 = 0; k0 < 512; k0 += 64) {
    const unsigned short* xa = xb + (size_t)m0 * 512 + k0;
    const unsigned short* wz = W + (size_t)n0 * 512 + k0;
    __syncthreads();
#pragma unroll
    for (int rr = 0; rr < 4; ++rr) {
      int cb = rr * 256 + w * 64;
      int s = cb + l;
      int row = s >> 3, c = (s & 7) ^ (row & 7);
      gload_lds16(&xa[(size_t)row * 512 + c * 8], &As[cb * 8]);
      gload_lds16(&wz[(size_t)row * 512 + c * 8], &Bs[cb * 8]);
    }
    __syncthreads();
#pragma unroll
    for (int ka = 0; ka < 2; ++ka) {
      u4bf af[4];
#pragma unroll
      for (int mt = 0; mt < 4; ++mt) {
        int row = wm * 64 + mt * 16 + lm;
        af[mt].u = *(const uint4*)&As[row * 64 + (((ka * 4 + lq) ^ (row & 7)) * 8)];
      }
#pragma unroll
      for (int nt = 0; nt < 4; ++nt) {
        int row = wn * 64 + nt * 16 + lm;
        u4bf bfv;
        bfv.u = *(const uint4*)&Bs[row * 64 + (((ka * 4 + lq) ^ (row & 7)) * 8)];
#pragma unroll
        for (int mt = 0; mt < 4; ++mt) acc[mt][nt] = MFMA16(af[mt].v, bfv.v, acc[mt][nt]);
      }
    }
  }
  const float m = (z == 0) ? 0.06376695f : 1.0f;  // 512^-0.5 * log2(e) for Q
#pragma unroll
  for (int mt = 0; mt < 4; ++mt)
#pragma unroll
    for (int reg = 0; reg < 4; ++reg) {
      int row = m0 + wm * 64 + mt * 16 + lq * 4 + reg;
      uint2 v = make_uint2(
          pk2bf(acc[mt][0][reg] * m, acc[mt][1][reg] * m),
          pk2bf(acc[mt][2][reg] * m, acc[mt][3][reg] * m));
      *(uint2*)&out[(size_t)row * 512 + n0 + wn * 64 + lm * 4] = v;
    }
}

// ---------------------------------------------------------------------------
// V transpose with t-permutation baked in; input V arrives d-permuted
// (d' = (d&15)*4 + d>>4) so the output row is relabeled d = (d'&3)*16+(d'>>2)
// (free). grid (32, 8, 4), 256 thr.
// ---------------------------------------------------------------------------
__global__ __launch_bounds__(256) void v_transpose(
    const unsigned short* __restrict__ v, unsigned short* __restrict__ vt)
{
  const int s0 = blockIdx.x * 64, c0 = blockIdx.y * 64, b = blockIdx.z;
  __shared__ __align__(16) unsigned short T[64 * 72];
  const int tid = threadIdx.x;
  for (int idx = tid; idx < 512; idx += 256) {
    int r = idx >> 3, c8 = (idx & 7) * 8;
    *(uint4*)&T[r * 72 + c8] =
        *(const uint4*)&v[(size_t)(b * 2048 + s0 + r) * 512 + c0 + c8];
  }
  __syncthreads();
  for (int idx = tid; idx < 512; idx += 256) {
    int dp = idx >> 3, s8 = (idx & 7) * 8;
    int d = (dp & 3) * 16 + (dp >> 2);  // un-permute
    union { unsigned short u[8]; uint4 q; } tmp;
#pragma unroll
    for (int j = 0; j < 8; ++j) {
      int p = s8 + j;
      int tsrc = (p & 3) * 16 + (p >> 2);
      tmp.u[j] = T[tsrc * 72 + dp];
    }
    *(uint4*)&vt[((size_t)(b * 512) + c0 + d) * 2048 + s0 + s8] = tmp.q;
  }
}

// ---------------------------------------------------------------------------
// Fused attention (R5 structure + R6's validated deltas).
// Max-free softmax (Q pre-scaled by scale*log2e, raw v_exp_f32); l via ones-B
// MFMA. K/V^T staged via global_load_lds; Er B-fragments direct from global
// with ONE-ITER register prefetch (R6 lesson: unprefetched global fragments
// on the MFMA path are latency death). 2 barriers/iter; Ps rows are
// wave-private so the P->PV dependency needs only a compiler fence.
// Circular Rx[slot=ai&127][isel], stride 68:
//   ai<64: Er[1984+ai]; ai==64: zero row erb[2048]; ai>64: Er[ai-65], isel=il+1.
// ---------------------------------------------------------------------------
__global__ __launch_bounds__(256, 3) void attn_mfma(
    const unsigned short* __restrict__ qw, const unsigned short* __restrict__ kw,
    const unsigned short* __restrict__ vt, const unsigned short* __restrict__ erb,
    float* __restrict__ out)
{
  const int qb = blockIdx.x, bh = blockIdx.y;
  const int b = bh >> 3, h = bh & 7;
  const int i0 = qb * 64;

  __shared__ __align__(16) unsigned short Ks[64 * 64];   // [t][d'] swizzled
  __shared__ __align__(16) unsigned short VTs[64 * 64];  // [d][t'] swizzled
  __shared__ __align__(16) unsigned short Ps[64 * 72];   // P [i][t'] wave-private rows
  __shared__ __align__(16) unsigned short Rx[128 * 68];  // [slot][isel]

  const int tid = threadIdx.x;
  const int w = tid >> 6, l = tid & 63, lm = l & 15, lq = l >> 4;

  const unsigned short* qbase = qw + ((size_t)(b * 2048)) * 512 + h * 64;
  const unsigned short* kbase = kw + ((size_t)(b * 2048)) * 512 + h * 64;
  const unsigned short* vtb = vt + ((size_t)(b * 512 + h * 64)) * 2048;

  union u4bf { uint4 u; bf16x8 v; };

  u4bf ones;
  ones.u = make_uint4(0x3F803F80u, 0x3F803F80u, 0x3F803F80u, 0x3F803F80u);

  // ---- loop-invariant address constants ----
  const int ko0 = (lq ^ (lm & 7)) * 8;        // swizzled frag offset, ka=0
  const int ko1 = ((4 + lq) ^ (lm & 7)) * 8;  // ka=1
  const int apa = (w * 16 + lm) * 72 + lq * 8;  // ap read base (ka*32 added)
  // gather constants: cn[reg][nt] = 63 + lm - il + 16*nt, il = w*16+lq*4+reg
  int cn0[4], il_[4], psa[4];
#pragma unroll
  for (int reg = 0; reg < 4; ++reg) {
    il_[reg] = w * 16 + lq * 4 + reg;
    cn0[reg] = 63 + lm - il_[reg];
    psa[reg] = il_[reg] * 72 + lm * 4;
  }

  // ---- wave's own QK A-fragment ----
  u4bf aqw[2];
  {
    int gi = i0 + w * 16 + lm;
    aqw[0].u = *(const uint4*)&qbase[(size_t)gi * 512 + lq * 8];
    aqw[1].u = *(const uint4*)&qbase[(size_t)gi * 512 + 32 + lq * 8];
  }
  // ---- Q-ext fragments for rslab (rows rt*16+lm; >64 or OOB -> 0),
  //      constant-indexed ONLY (R2 lesson) ----
  u4bf aq[5][2];
#pragma unroll
  for (int rt = 0; rt < 5; ++rt) {
    int row = rt * 16 + lm, gi = i0 + row;
#pragma unroll
    for (int ka = 0; ka < 2; ++ka) {
      if (row <= 64 && gi < 2048)
        aq[rt][ka].u = *(const uint4*)&qbase[(size_t)gi * 512 + ka * 32 + lq * 8];
      else
        aq[rt][ka].u = make_uint4(0, 0, 0, 0);
    }
  }

  auto stageTile = [&](const unsigned short* srcBase, size_t srcStride,
                       unsigned short* dst) {
#pragma unroll
    for (int rr = 0; rr < 2; ++rr) {
      int cb = rr * 256 + w * 64;
      int s = cb + l;
      int row = s >> 3, c = (s & 7) ^ (row & 7);
      gload_lds16(&srcBase[(size_t)row * srcStride + c * 8], &dst[cb * 8]);
    }
  };
  auto loadBe = [&](int A0, u4bf& be0, u4bf& be1) {
    int ai = A0 + w * 16 + lm;
    int g = (ai < 64) ? (1984 + ai) : (ai == 64 ? 2048 : ai - 65);
    const unsigned short* ep = &erb[(size_t)g * 64];
    be0.u = *(const uint4*)&ep[lq * 8];
    be1.u = *(const uint4*)&ep[32 + lq * 8];
  };
  auto rslabCompute = [&](int A0, u4bf be0, u4bf be1) {
    f32x4 rc[5];
#pragma unroll
    for (int rt = 0; rt < 5; ++rt) rc[rt] = (f32x4){0.f, 0.f, 0.f, 0.f};
    rc[0] = MFMA16(aq[0][0].v, be0.v, rc[0]);
    rc[0] = MFMA16(aq[0][1].v, be1.v, rc[0]);
    rc[1] = MFMA16(aq[1][0].v, be0.v, rc[1]);
    rc[1] = MFMA16(aq[1][1].v, be1.v, rc[1]);
    rc[2] = MFMA16(aq[2][0].v, be0.v, rc[2]);
    rc[2] = MFMA16(aq[2][1].v, be1.v, rc[2]);
    rc[3] = MFMA16(aq[3][0].v, be0.v, rc[3]);
    rc[3] = MFMA16(aq[3][1].v, be1.v, rc[3]);
    rc[4] = MFMA16(aq[4][0].v, be0.v, rc[4]);
    rc[4] = MFMA16(aq[4][1].v, be1.v, rc[4]);
    int slot = (A0 + w * 16 + lm) & 127;
    unsigned short* rp = &Rx[slot * 68 + lq * 4];
    *(unsigned*)&rp[0]  = pk2bf(rc[0][0], rc[0][1]);
    *(unsigned*)&rp[2]  = pk2bf(rc[0][2], rc[0][3]);
    *(unsigned*)&rp[16] = pk2bf(rc[1][0], rc[1][1]);
    *(unsigned*)&rp[18] = pk2bf(rc[1][2], rc[1][3]);
    *(unsigned*)&rp[32] = pk2bf(rc[2][0], rc[2][1]);
    *(unsigned*)&rp[34] = pk2bf(rc[2][2], rc[2][3]);
    *(unsigned*)&rp[48] = pk2bf(rc[3][0], rc[3][1]);
    *(unsigned*)&rp[50] = pk2bf(rc[3][2], rc[3][3]);
    if (lq == 0) Rx[slot * 68 + 64] = (unsigned short)f2bfu(rc[4][0]);
  };

  // ---- prefill Rx with ai in [-i0, -i0+127] (disjoint slots) ----
  {
    u4bf b0, b1;
    loadBe(-i0, b0, b1);
    rslabCompute(-i0, b0, b1);
    loadBe(-i0 + 64, b0, b1);
    rslabCompute(-i0 + 64, b0, b1);
  }
  // prefetch Er B-fragments for tb=1 (A0 = -i0+127)
  u4bf pb0, pb1;
  loadBe(-i0 + 127, pb0, pb1);

  f32x4 O[5];  // O[4] = row-sum l accumulator
#pragma unroll
  for (int a = 0; a < 5; ++a) O[a] = (f32x4){0.f, 0.f, 0.f, 0.f};

  for (int tb = 0; tb < 32; ++tb) {
    const int t0 = tb * 64, dbase = t0 - i0;
    __syncthreads();  // (a) prior-iter consumers (QK/PV/gather) done

    stageTile(kbase + (size_t)t0 * 512, 512, Ks);
    stageTile(vtb + t0, 2048, VTs);
    if (tb > 0) {
      rslabCompute(dbase + 63, pb0, pb1);
      if (tb < 31) loadBe(dbase + 127, pb0, pb1);  // prefetch next iter
    }
    __syncthreads();  // (b) staging DMA drained + Rx visible

    // ---- QK^T (hoisted swizzle offsets) ----
    f32x4 sc[4];
#pragma unroll
    for (int nt = 0; nt < 4; ++nt) {
      int rb = (nt * 16 + lm) * 64;
      u4bf bk0, bk1;
      bk0.u = *(const uint4*)&Ks[rb + ko0];
      bk1.u = *(const uint4*)&Ks[rb + ko1];
      sc[nt] = (f32x4){0.f, 0.f, 0.f, 0.f};
      sc[nt] = MFMA16(aqw[0].v, bk0.v, sc[nt]);
      sc[nt] = MFMA16(aqw[1].v, bk1.v, sc[nt]);
    }

    // ---- skew gather + exp2, packed b64 P-write (wave-private rows) ----
#pragma unroll
    for (int reg = 0; reg < 4; ++reg) {
      const int aib = dbase + cn0[reg];
      const int il = il_[reg];
      float pv[4];
#pragma unroll
      for (int nt = 0; nt < 4; ++nt) {
        int ai = aib + nt * 16;
        int isel = il + (ai >= 65 ? 1 : 0);
        float rel = bf2f(Rx[(ai & 127) * 68 + isel]);
        pv[nt] = fast_exp2(sc[nt][reg] + rel);
      }
      *(uint2*)&Ps[psa[reg]] =
          make_uint2(pk2bf(pv[0], pv[1]), pk2bf(pv[2], pv[3]));
    }
    __asm__ __volatile__("" ::: "memory");  // same-wave DS RAW: in-order DS pipe

    // ---- PV + l (ones from registers) ----
#pragma unroll
    for (int ka = 0; ka < 2; ++ka) {
      u4bf ap;
      ap.u = *(const uint4*)&Ps[apa + ka * 32];
#pragma unroll
      for (int nt = 0; nt < 4; ++nt) {
        int rb = (nt * 16 + lm) * 64;
        u4bf bv;
        bv.u = *(const uint4*)&VTs[rb + (ka == 0 ? ko0 : ko1)];
        O[nt] = MFMA16(ap.v, bv.v, O[nt]);
      }
      O[4] = MFMA16(ap.v, ones.v, O[4]);
    }
  }

  // epilogue: every lane holds l in O[4][reg]
  float* ob = out + ((size_t)(b * 2048) + i0) * 512 + h * 64;
#pragma unroll
  for (int reg = 0; reg < 4; ++reg) {
    float inv = 1.f / O[4][reg];
#pragma unroll
    for (int nt = 0; nt < 4; ++nt)
      ob[(size_t)il_[reg] * 512 + nt * 16 + lm] = O[nt][reg] * inv;
  }
}

// ---------------------------------------------------------------------------
// In-place LayerNorm over E=512 per (b,s) row. grid 8192, block 256.
// ---------------------------------------------------------------------------
__global__ __launch_bounds__(256) void ln_kernel(
    float* __restrict__ io, const float* __restrict__ gamma,
    const float* __restrict__ beta)
{
  const int row = blockIdx.x;
  float* xr = io + (size_t)row * 512;
  const int tid = threadIdx.x;
  float2 v = *(const float2*)&xr[tid * 2];
  float s = v.x + v.y;
  float sq = v.x * v.x + v.y * v.y;
#pragma unroll
  for (int off = 1; off < 64; off <<= 1) {
    s += __shfl_xor(s, off, 64);
    sq += __shfl_xor(sq, off, 64);
  }
  __shared__ float red[8];
  const int wid = tid >> 6, lane = tid & 63;
  if (lane == 0) { red[wid] = s; red[wid + 4] = sq; }
  __syncthreads();
  s = red[0] + red[1] + red[2] + red[3];
  sq = red[4] + red[5] + red[6] + red[7];
  const float mean = s * (1.f / 512.f);
  float var = sq * (1.f / 512.f) - mean * mean;
  var = fmaxf(var, 0.f);
  const float rstd = rsqrtf(var + 1e-5f);
  float2 g = *(const float2*)&gamma[tid * 2];
  float2 be = *(const float2*)&beta[tid * 2];
  float2 o;
  o.x = (v.x - mean) * rstd * g.x + be.x;
  o.y = (v.y - mean) * rstd * g.y + be.y;
  *(float2*)&xr[tid * 2] = o;
}

extern "C" void kernel_launch(void* const* d_in, const int* in_sizes, int n_in,
                              void* d_out, int out_size, void* d_ws, size_t ws_size,
                              hipStream_t stream) {
  const float* x     = (const float*)d_in[0];
  const float* Wq    = (const float*)d_in[1];
  const float* Wk    = (const float*)d_in[2];
  const float* Wv    = (const float*)d_in[3];
  const float* Er    = (const float*)d_in[4];
  const float* gamma = (const float*)d_in[5];
  const float* beta  = (const float*)d_in[6];
  float* out = (float*)d_out;

  // ws layout (bf16 shorts): qkv 3*8192*512 | vT 4*512*2048 | erb 2049*64 |
  //                          xb 8192*512 | wb 3*512*512      (~41.8 MB)
  unsigned short* qkvb = (unsigned short*)d_ws;
  unsigned short* vtb  = qkvb + (size_t)3 * 8192 * 512;
  unsigned short* erb  = vtb + (size_t)4 * 512 * 2048;
  unsigned short* xb   = erb + (size_t)2049 * 64;
  unsigned short* wb   = xb + (size_t)8192 * 512;
  unsigned short* vb   = qkvb + (size_t)2 * 8192 * 512;

  conv_all<<<dim3(2497), 256, 0, stream>>>(x, Wq, Wk, Wv, Er, xb, wb, erb);
  qkv_gemm_mfma<<<dim3(64, 4, 3), 256, 0, stream>>>(xb, wb, qkvb);
  v_transpose<<<dim3(32, 8, 4), 256, 0, stream>>>(vb, vtb);
  attn_mfma<<<dim3(32, 32), 256, 0, stream>>>(qkvb, qkvb + (size_t)8192 * 512, vtb, erb, out);
  ln_kernel<<<dim3(8192), 256, 0, stream>>>(out, gamma, beta);
}